// Round 11
// baseline (364.898 us; speedup 1.0000x reference)
//
#include <hip/hip_runtime.h>
#include <hip/hip_bf16.h>

#define NN 50000
#define EE 800000
#define IN_DIM 256
#define HID 64
#define HEADS 6
#define D1 384            // HEADS*HID
#define OUT_DIM 32
#define NEG_SLOPE 0.2f
#define CAP 128           // edge chunk per node held in LDS
#define NBLK 196          // ceil(50000/256)

typedef unsigned int uint32;
typedef unsigned short ushort_t;
typedef short short8 __attribute__((ext_vector_type(8)));
typedef float f32x4 __attribute__((ext_vector_type(4)));
typedef float f32x2 __attribute__((ext_vector_type(2)));
typedef ushort_t ushort8 __attribute__((ext_vector_type(8)));

__device__ __forceinline__ ushort_t f2bf(float f) {
    uint32 u = __builtin_bit_cast(uint32, f);
    u += 0x7fffu + ((u >> 16) & 1u);
    return (ushort_t)(u >> 16);
}
__device__ __forceinline__ float bf2f(ushort_t s) {
    uint32 u = ((uint32)s) << 16;
    return __builtin_bit_cast(float, u);
}
// dword d holds std channels (2d) in low half, (2d+1) in high half
__device__ __forceinline__ float lo16(uint32 d) { return __builtin_bit_cast(float, d << 16); }
__device__ __forceinline__ float hi16(uint32 d) { return __builtin_bit_cast(float, d & 0xffff0000u); }

// ---------------- fused prep: w1t (blocks 0..95), w2t (96..143), deg=0 (144..339) ----------------

__global__ __launch_bounds__(256) void prep_kernel(const float* __restrict__ W1,
                                                   ushort_t* __restrict__ W1Tb,
                                                   const float* __restrict__ W2,
                                                   ushort_t* __restrict__ W2Tb,
                                                   int* __restrict__ deg) {
    int bx = blockIdx.x;
    if (bx < 96) {
        __shared__ float tile[32][33];
        int tx = threadIdx.x & 31, ty = threadIdx.x >> 5;   // 32x8
        int n0 = (bx % 12) * 32;
        int k0 = (bx / 12) * 32;
#pragma unroll
        for (int i = 0; i < 4; ++i)
            tile[ty + i * 8][tx] = W1[(k0 + ty + i * 8) * D1 + n0 + tx];
        __syncthreads();
#pragma unroll
        for (int i = 0; i < 4; ++i)
            W1Tb[(n0 + ty + i * 8) * IN_DIM + k0 + tx] = f2bf(tile[tx][ty + i * 8]);
    } else if (bx < 144) {
        int idx = (bx - 96) * 256 + threadIdx.x;   // 0..12287
        if (idx < D1 * OUT_DIM) {
            int k = idx >> 5, n = idx & 31;
            W2Tb[n * D1 + k] = f2bf(W2[idx]);
        }
    } else {
        int i = (bx - 144) * 256 + threadIdx.x;
        if (i < NN) deg[i] = 0;
    }
}

// ---------------- CSR build ----------------

__global__ void hist_kernel(const int* __restrict__ dst, int* __restrict__ deg) {
    int i = blockIdx.x * 256 + threadIdx.x;
    if (i < EE) atomicAdd(&deg[dst[i]], 1);
}

// deg is read-side +1 (self-loop).
__global__ __launch_bounds__(256) void scan1_kernel(const int* __restrict__ deg,
                                                    int* __restrict__ blockSums) {
    int t = threadIdx.x;
    int i = blockIdx.x * 256 + t;
    int v = (i < NN) ? (deg[i] + 1) : 0;
#pragma unroll
    for (int o = 32; o; o >>= 1) v += __shfl_xor(v, o);
    __shared__ int ws[4];
    if ((t & 63) == 0) ws[t >> 6] = v;
    __syncthreads();
    if (t == 0) blockSums[blockIdx.x] = ws[0] + ws[1] + ws[2] + ws[3];
}

__global__ __launch_bounds__(256) void scan2_kernel(const int* __restrict__ blockSums,
                                                    int* __restrict__ blockPrefix,
                                                    int* __restrict__ offsets) {
    int t = threadIdx.x;
    int lane = t & 63, w = t >> 6;
    int v = (t < NBLK) ? blockSums[t] : 0;
    int x = v;
#pragma unroll
    for (int o = 1; o < 64; o <<= 1) {
        int y = __shfl_up(x, o);
        if (lane >= o) x += y;
    }
    __shared__ int ws[4];
    if (lane == 63) ws[w] = x;
    __syncthreads();
    int wpre = 0;
#pragma unroll
    for (int k = 0; k < 4; ++k) if (k < w) wpre += ws[k];
    int incl = x + wpre;
    if (t < NBLK) blockPrefix[t] = incl - v;
    if (t == NBLK - 1) offsets[NN] = incl;   // total == EE+NN
}

__global__ __launch_bounds__(256) void scan3_kernel(const int* __restrict__ deg,
                                                    const int* __restrict__ blockPrefix,
                                                    int* __restrict__ offsets,
                                                    int* __restrict__ cursor) {
    int t = threadIdx.x;
    int i = blockIdx.x * 256 + t;
    int lane = t & 63, w = t >> 6;
    int v = (i < NN) ? (deg[i] + 1) : 0;
    int x = v;
#pragma unroll
    for (int o = 1; o < 64; o <<= 1) {
        int y = __shfl_up(x, o);
        if (lane >= o) x += y;
    }
    __shared__ int ws[4];
    if (lane == 63) ws[w] = x;
    __syncthreads();
    int wpre = 0;
#pragma unroll
    for (int k = 0; k < 4; ++k) if (k < w) wpre += ws[k];
    int excl = x + wpre - v + blockPrefix[blockIdx.x];
    if (i < NN) { offsets[i] = excl; cursor[i] = excl; }
}

__global__ void scatter_kernel(const int* __restrict__ src, const int* __restrict__ dst,
                               int* __restrict__ cursor, int* __restrict__ srcIdx) {
    int i = blockIdx.x * 256 + threadIdx.x;
    if (i >= EE + NN) return;
    int s, d;
    if (i < EE) { s = src[i]; d = dst[i]; }
    else        { s = i - EE; d = s; }
    int pos = atomicAdd(&cursor[d], 1);
    srcIdx[pos] = s;
}

// ---------------- GEMM1: H1b = bf16( x @ W1 ) via MFMA, fused a_src1/a_dst1 ----------------
// 128-row x 384-col block tile, 512 threads = 8 waves: rg=wid>>2 (row half), cg=wid&3 (96-col group).

#define G1_BM 128
#define G1_BK 64

__global__ __launch_bounds__(512) void gemm1_kernel(const float* __restrict__ A,
                                                    const ushort_t* __restrict__ Bt,
                                                    const float* __restrict__ att_src,
                                                    const float* __restrict__ att_dst,
                                                    ushort_t* __restrict__ Cb,
                                                    float* __restrict__ a_src1,
                                                    float* __restrict__ a_dst1) {
    __shared__ __align__(16) ushort_t As[G1_BM][G1_BK];   // 16 KB, 16B-chunk XOR swizzle
    __shared__ __align__(16) ushort_t Bs[D1][G1_BK];      // 48 KB, same swizzle
    __shared__ float redS[G1_BM][8];                      // 4 KB: [row][cg*2+headslot]
    __shared__ float redD[G1_BM][8];                      // 4 KB
    int t = threadIdx.x;
    int m0 = blockIdx.x * G1_BM;
    int wid = t >> 6, lane = t & 63;
    int rg = wid >> 2, cg = wid & 3;
    int lrow = lane & 15, lk = lane >> 4;
    f32x4 acc[4][6] = {};
    for (int k0 = 0; k0 < IN_DIM; k0 += G1_BK) {
        {
            int r = t >> 3, c = t & 7;
#pragma unroll
            for (int p = 0; p < 2; ++p) {
                int row = p * 64 + r;
                int gr = m0 + row;
                float4 v0 = make_float4(0.f, 0.f, 0.f, 0.f), v1 = v0;
                if (gr < NN) {
                    const float* g = &A[(size_t)gr * IN_DIM + k0 + c * 8];
                    v0 = *reinterpret_cast<const float4*>(g);
                    v1 = *reinterpret_cast<const float4*>(g + 4);
                }
                ushort8 u;
                u[0] = f2bf(v0.x); u[1] = f2bf(v0.y); u[2] = f2bf(v0.z); u[3] = f2bf(v0.w);
                u[4] = f2bf(v1.x); u[5] = f2bf(v1.y); u[6] = f2bf(v1.z); u[7] = f2bf(v1.w);
                *reinterpret_cast<ushort8*>(&As[row][(c ^ (row & 7)) * 8]) = u;
            }
        }
        {
            int r = t >> 3, c = t & 7;
#pragma unroll
            for (int p = 0; p < 6; ++p) {
                int row = p * 64 + r;
                ushort8 u = *reinterpret_cast<const ushort8*>(&Bt[row * IN_DIM + k0 + c * 8]);
                *reinterpret_cast<ushort8*>(&Bs[row][(c ^ (row & 7)) * 8]) = u;
            }
        }
        __syncthreads();
#pragma unroll
        for (int kk = 0; kk < G1_BK; kk += 32) {
            int ckb = (kk >> 3) + lk;
            short8 af[4];
#pragma unroll
            for (int fm = 0; fm < 4; ++fm) {
                int m = rg * 64 + fm * 16 + lrow;
                af[fm] = *reinterpret_cast<const short8*>(&As[m][(ckb ^ (m & 7)) * 8]);
            }
#pragma unroll
            for (int fn = 0; fn < 6; ++fn) {
                int n = cg * 96 + fn * 16 + lrow;
                short8 bfv = *reinterpret_cast<const short8*>(&Bs[n][(ckb ^ (n & 7)) * 8]);
#pragma unroll
                for (int fm = 0; fm < 4; ++fm)
                    acc[fm][fn] = __builtin_amdgcn_mfma_f32_16x16x32_bf16(af[fm], bfv, acc[fm][fn], 0, 0, 0);
            }
        }
        __syncthreads();
    }
    float atS[6], atD[6];
#pragma unroll
    for (int fn = 0; fn < 6; ++fn) {
        int col = cg * 96 + fn * 16 + lrow;
        atS[fn] = att_src[col];
        atD[fn] = att_dst[col];
    }
    int split = (cg & 1) ? 2 : 4;   // fn < split -> headslot 0, else headslot 1
#pragma unroll
    for (int fm = 0; fm < 4; ++fm) {
#pragma unroll
        for (int r = 0; r < 4; ++r) {
            int rowl = rg * 64 + fm * 16 + lk * 4 + r;
            int row = m0 + rowl;
            float vsA = 0.f, vsB = 0.f, vdA = 0.f, vdB = 0.f;
#pragma unroll
            for (int fn = 0; fn < 6; ++fn) {
                float v = acc[fm][fn][r];
                if (fn < split) { vsA += v * atS[fn]; vdA += v * atD[fn]; }
                else            { vsB += v * atS[fn]; vdB += v * atD[fn]; }
            }
#pragma unroll
            for (int o = 8; o; o >>= 1) {
                vsA += __shfl_xor(vsA, o); vsB += __shfl_xor(vsB, o);
                vdA += __shfl_xor(vdA, o); vdB += __shfl_xor(vdB, o);
            }
            if (lrow == 0) {
                redS[rowl][cg * 2 + 0] = vsA; redS[rowl][cg * 2 + 1] = vsB;
                redD[rowl][cg * 2 + 0] = vdA; redD[rowl][cg * 2 + 1] = vdB;
            }
            if (row < NN) {
#pragma unroll
                for (int fn = 0; fn < 6; ++fn) {
                    int col = cg * 96 + fn * 16 + lrow;
                    Cb[(size_t)row * D1 + col] = f2bf(acc[fm][fn][r]);
                }
            }
        }
    }
    __syncthreads();
    if (t < G1_BM) {
        int row = m0 + t;
        if (row < NN) {
            // head <- slot mapping: h0=s0; h1=s1+s2; h2=s3; h3=s4; h4=s5+s6; h5=s7
            float s0 = redS[t][0], s1 = redS[t][1] + redS[t][2], s2 = redS[t][3];
            float s3 = redS[t][4], s4 = redS[t][5] + redS[t][6], s5 = redS[t][7];
            float d0 = redD[t][0], d1 = redD[t][1] + redD[t][2], d2 = redD[t][3];
            float d3 = redD[t][4], d4 = redD[t][5] + redD[t][6], d5 = redD[t][7];
            float* ps = &a_src1[(size_t)row * HEADS];
            float* pd = &a_dst1[(size_t)row * HEADS];
            ps[0] = s0; ps[1] = s1; ps[2] = s2; ps[3] = s3; ps[4] = s4; ps[5] = s5;
            pd[0] = d0; pd[1] = d1; pd[2] = d2; pd[3] = d3; pd[4] = d4; pd[5] = d5;
        }
    }
}

// ---------------- layer-1 aggregation + fused GEMM2 epilogue ----------------
// Two-phase exp-direct softmax aggregation (as r8), then per-wave 384x32 GEMV
// against W2T (24 KB, L1-resident) producing H2 row + a_src2/a_dst2 directly.
// OUT1 is never materialized in global memory.

__global__ __launch_bounds__(256, 4) void agg1_kernel(const uint32* __restrict__ H1d,
                                                      const float* __restrict__ a_src,
                                                      const float* __restrict__ a_dst,
                                                      const int* __restrict__ offsets,
                                                      const int* __restrict__ srcIdx,
                                                      const float* __restrict__ b1,
                                                      const ushort_t* __restrict__ W2Tb,
                                                      const float* __restrict__ att_src2,
                                                      const float* __restrict__ att_dst2,
                                                      ushort_t* __restrict__ H2b,
                                                      float* __restrict__ a_src2,
                                                      float* __restrict__ a_dst2) {
    __shared__ float pl[4][HEADS][CAP + 1];   // ~12.4 KB
    __shared__ int   sl[4][CAP];              // 2 KB
    __shared__ uint32 rowbuf[4][192];         // 3 KB: packed bf16 out-row per wave
    int w = threadIdx.x >> 6, lane = threadIdx.x & 63;
    int hb = lane >> 5;
    int n = blockIdx.x * 4 + w;
    const float2* asv = (const float2*)a_src;
    float ad[HEADS];
#pragma unroll
    for (int h = 0; h < HEADS; ++h) ad[h] = a_dst[n * HEADS + h];
    float ldn[HEADS] = {0.f, 0.f, 0.f, 0.f, 0.f, 0.f};
    float acc[6] = {0.f, 0.f, 0.f, 0.f, 0.f, 0.f};
    int beg = offsets[n], end = offsets[n + 1];
    for (int cbeg = beg; cbeg < end; cbeg += CAP) {
        int L = end - cbeg; if (L > CAP) L = CAP;
        // ---- phase A: lanes over edges ----
        for (int tI = lane; tI < L; tI += 64) {
            int s = srcIdx[cbeg + tI];
            sl[w][tI] = s;
            float2 e0 = asv[s * 3 + 0];
            float2 e1 = asv[s * 3 + 1];
            float2 e2 = asv[s * 3 + 2];
            float ev[6] = {e0.x, e0.y, e1.x, e1.y, e2.x, e2.y};
#pragma unroll
            for (int h = 0; h < HEADS; ++h) {
                float e = ev[h] + ad[h];
                e = e > 0.f ? e : NEG_SLOPE * e;
                float p = __expf(e);
                pl[w][h][tI] = p;
                ldn[h] += p;
            }
        }
        // ---- phase B: lanes over dwords, 4 edges / 12 gathers in flight ----
        int j = 0;
        for (; j + 4 <= L; j += 4) {
            int s0 = sl[w][j], s1 = sl[w][j + 1], s2 = sl[w][j + 2], s3 = sl[w][j + 3];
            const uint32* h0 = H1d + (size_t)s0 * 192 + lane;
            const uint32* h1 = H1d + (size_t)s1 * 192 + lane;
            const uint32* h2 = H1d + (size_t)s2 * 192 + lane;
            const uint32* h3 = H1d + (size_t)s3 * 192 + lane;
            uint32 a0 = h0[0], a1 = h0[64], a2 = h0[128];
            uint32 b0 = h1[0], b1v_ = h1[64], b2 = h1[128];
            uint32 c0 = h2[0], c1 = h2[64], c2 = h2[128];
            uint32 d0 = h3[0], d1 = h3[64], d2 = h3[128];
            float p00 = pl[w][hb][j],     p01 = pl[w][2 + hb][j],     p02 = pl[w][4 + hb][j];
            float p10 = pl[w][hb][j + 1], p11 = pl[w][2 + hb][j + 1], p12 = pl[w][4 + hb][j + 1];
            float p20 = pl[w][hb][j + 2], p21 = pl[w][2 + hb][j + 2], p22 = pl[w][4 + hb][j + 2];
            float p30 = pl[w][hb][j + 3], p31 = pl[w][2 + hb][j + 3], p32 = pl[w][4 + hb][j + 3];
            acc[0] += p00 * lo16(a0); acc[1] += p00 * hi16(a0);
            acc[2] += p01 * lo16(a1); acc[3] += p01 * hi16(a1);
            acc[4] += p02 * lo16(a2); acc[5] += p02 * hi16(a2);
            acc[0] += p10 * lo16(b0); acc[1] += p10 * hi16(b0);
            acc[2] += p11 * lo16(b1v_); acc[3] += p11 * hi16(b1v_);
            acc[4] += p12 * lo16(b2); acc[5] += p12 * hi16(b2);
            acc[0] += p20 * lo16(c0); acc[1] += p20 * hi16(c0);
            acc[2] += p21 * lo16(c1); acc[3] += p21 * hi16(c1);
            acc[4] += p22 * lo16(c2); acc[5] += p22 * hi16(c2);
            acc[0] += p30 * lo16(d0); acc[1] += p30 * hi16(d0);
            acc[2] += p31 * lo16(d1); acc[3] += p31 * hi16(d1);
            acc[4] += p32 * lo16(d2); acc[5] += p32 * hi16(d2);
        }
        for (; j < L; ++j) {
            int s0 = sl[w][j];
            const uint32* h0 = H1d + (size_t)s0 * 192 + lane;
            uint32 x0 = h0[0], x1 = h0[64], x2 = h0[128];
            float p0 = pl[w][hb][j], p1 = pl[w][2 + hb][j], p2 = pl[w][4 + hb][j];
            acc[0] += p0 * lo16(x0); acc[1] += p0 * hi16(x0);
            acc[2] += p1 * lo16(x1); acc[3] += p1 * hi16(x1);
            acc[4] += p2 * lo16(x2); acc[5] += p2 * hi16(x2);
        }
    }
#pragma unroll
    for (int h = 0; h < HEADS; ++h) {
#pragma unroll
        for (int o = 32; o; o >>= 1) ldn[h] += __shfl_xor(ldn[h], o);
    }
    float dsel[3];
#pragma unroll
    for (int k = 0; k < 3; ++k) dsel[k] = hb ? ldn[2 * k + 1] : ldn[2 * k];
    const float2* b1v = (const float2*)b1;
#pragma unroll
    for (int k = 0; k < 3; ++k) {
        float2 bb = b1v[k * 64 + lane];
        float v0 = fmaxf(acc[2 * k]     / dsel[k] + bb.x, 0.f);
        float v1 = fmaxf(acc[2 * k + 1] / dsel[k] + bb.y, 0.f);
        rowbuf[w][k * 64 + lane] = (uint32)f2bf(v0) | ((uint32)f2bf(v1) << 16);
    }
    __syncthreads();   // order rowbuf writes before cross-lane reads (all threads reach here)
    // ---- fused GEMM2 GEMV: h2[c] = sum_k out1[k] * W2T[c][k] ----
    int c = lane & 31, half = lane >> 5;
    const uint32* w2d = (const uint32*)W2Tb + c * 192 + half * 96;
    const uint32* rb = &rowbuf[w][half * 96];
    float hacc = 0.f;
#pragma unroll 8
    for (int j = 0; j < 96; ++j) {
        uint32 rw = rb[j];
        uint32 ww = w2d[j];
        hacc += lo16(rw) * lo16(ww) + hi16(rw) * hi16(ww);
    }
    hacc += __shfl_xor(hacc, 32);   // combine k-halves
    float vs = hacc * att_src2[c];
    float vd = hacc * att_dst2[c];
#pragma unroll
    for (int o = 16; o; o >>= 1) {
        vs += __shfl_xor(vs, o);
        vd += __shfl_xor(vd, o);
    }
    if (lane < 32) H2b[(size_t)n * OUT_DIM + c] = f2bf(hacc);
    if (lane == 0) { a_src2[n] = vs; a_dst2[n] = vd; }
}

// ---------------- layer-2 aggregation: exp-direct (+b2) -> d_out ----------------

__global__ __launch_bounds__(256, 4) void agg2_kernel(const ushort_t* __restrict__ H2b,
                                                      const float* __restrict__ a_src,
                                                      const float* __restrict__ a_dst,
                                                      const int* __restrict__ offsets,
                                                      const int* __restrict__ srcIdx,
                                                      const float* __restrict__ b2,
                                                      float* __restrict__ out) {
    __shared__ float pl[4][CAP];
    __shared__ int   sl[4][CAP];
    int w = threadIdx.x >> 6, lane = threadIdx.x & 63;
    int n = blockIdx.x * 4 + w;
    int q = lane & 15, par = lane >> 4;   // 4 edges in parallel, lane covers chans 2q,2q+1
    const uint32* H2d = (const uint32*)H2b;
    float ad = a_dst[n];
    float ldn = 0.f, ax = 0.f, ay = 0.f;
    int beg = offsets[n], end = offsets[n + 1];
    for (int cbeg = beg; cbeg < end; cbeg += CAP) {
        int L = end - cbeg; if (L > CAP) L = CAP;
        for (int tI = lane; tI < L; tI += 64) {
            int s = srcIdx[cbeg + tI];
            sl[w][tI] = s;
            float e = a_src[s] + ad;
            e = e > 0.f ? e : NEG_SLOPE * e;
            float p = __expf(e);
            pl[w][tI] = p;
            ldn += p;
        }
        int j = 0;
        for (; j + 8 <= L; j += 8) {
            int s0 = sl[w][j + par], s1 = sl[w][j + 4 + par];
            float p0 = pl[w][j + par], p1 = pl[w][j + 4 + par];
            uint32 d0 = H2d[(size_t)s0 * 16 + q];
            uint32 d1 = H2d[(size_t)s1 * 16 + q];
            ax += p0 * lo16(d0) + p1 * lo16(d1);
            ay += p0 * hi16(d0) + p1 * hi16(d1);
        }
        for (; j < L; j += 4) {
            int jj = j + par;
            if (jj < L) {
                int s = sl[w][jj];
                float p = pl[w][jj];
                uint32 d = H2d[(size_t)s * 16 + q];
                ax += p * lo16(d);
                ay += p * hi16(d);
            }
        }
    }
#pragma unroll
    for (int o = 32; o; o >>= 1) ldn += __shfl_xor(ldn, o);
    ax += __shfl_xor(ax, 16); ax += __shfl_xor(ax, 32);
    ay += __shfl_xor(ay, 16); ay += __shfl_xor(ay, 32);
    if (lane < 16) {
        float2 bb = ((const float2*)b2)[q];
        f32x2 o;
        o[0] = ax / ldn + bb.x;
        o[1] = ay / ldn + bb.y;
        __builtin_nontemporal_store(o, (f32x2*)&out[(size_t)n * 32 + q * 2]);
    }
}

// ---------------- launch ----------------

static inline size_t align256(size_t x) { return (x + 255) & ~size_t(255); }

extern "C" void kernel_launch(void* const* d_in, const int* in_sizes, int n_in,
                              void* d_out, int out_size, void* d_ws, size_t ws_size,
                              hipStream_t stream) {
    const float* x        = (const float*)d_in[0];
    const int*   ei       = (const int*)d_in[1];
    const float* W1       = (const float*)d_in[2];
    const float* att_src1 = (const float*)d_in[3];
    const float* att_dst1 = (const float*)d_in[4];
    const float* b1       = (const float*)d_in[5];
    const float* W2       = (const float*)d_in[6];
    const float* att_src2 = (const float*)d_in[7];
    const float* att_dst2 = (const float*)d_in[8];
    const float* b2       = (const float*)d_in[9];
    float* out = (float*)d_out;

    const int* e_src = ei;
    const int* e_dst = ei + EE;

    char* p = (char*)d_ws;
    ushort_t* H1b   = (ushort_t*)p; p += align256(sizeof(ushort_t) * (size_t)NN * D1);
    ushort_t* H2b   = (ushort_t*)p; p += align256(sizeof(ushort_t) * (size_t)NN * OUT_DIM);
    ushort_t* W1Tb  = (ushort_t*)p; p += align256(sizeof(ushort_t) * D1 * IN_DIM);
    ushort_t* W2Tb  = (ushort_t*)p; p += align256(sizeof(ushort_t) * D1 * OUT_DIM);
    float* AS1  = (float*)p; p += align256(sizeof(float) * NN * HEADS);
    float* AD1  = (float*)p; p += align256(sizeof(float) * NN * HEADS);
    float* AS2  = (float*)p; p += align256(sizeof(float) * NN);
    float* AD2  = (float*)p; p += align256(sizeof(float) * NN);
    int*   DEG  = (int*)p;   p += align256(sizeof(int) * NN);
    int*   OFF  = (int*)p;   p += align256(sizeof(int) * (NN + 1));
    int*   CUR  = (int*)p;   p += align256(sizeof(int) * NN);
    int*   BSUM = (int*)p;   p += align256(sizeof(int) * NBLK);
    int*   BPRE = (int*)p;   p += align256(sizeof(int) * NBLK);
    int*   SIDX = (int*)p;   p += align256(sizeof(int) * (EE + NN));

    // prep (w1t + w2t + deg=0 fused) then CSR build
    prep_kernel<<<340, 256, 0, stream>>>(W1, W1Tb, W2, W2Tb, DEG);
    hist_kernel<<<(EE + 255) / 256, 256, 0, stream>>>(e_dst, DEG);
    scan1_kernel<<<NBLK, 256, 0, stream>>>(DEG, BSUM);
    scan2_kernel<<<1, 256, 0, stream>>>(BSUM, BPRE, OFF);
    scan3_kernel<<<NBLK, 256, 0, stream>>>(DEG, BPRE, OFF, CUR);
    scatter_kernel<<<(EE + NN + 255) / 256, 256, 0, stream>>>(e_src, e_dst, CUR, SIDX);

    // layer 1 (+ fused layer-2 projection)
    gemm1_kernel<<<(NN + G1_BM - 1) / G1_BM, 512, 0, stream>>>(x, W1Tb, att_src1, att_dst1, H1b, AS1, AD1);
    agg1_kernel<<<NN / 4, 256, 0, stream>>>((const uint32*)H1b, AS1, AD1, OFF, SIDX, b1,
                                            W2Tb, att_src2, att_dst2, H2b, AS2, AD2);

    // layer 2 aggregation
    agg2_kernel<<<NN / 4, 256, 0, stream>>>(H2b, AS2, AD2, OFF, SIDX, b2, out);
}

// Round 12
// 313.237 us; speedup vs baseline: 1.1649x; 1.1649x over previous
//
#include <hip/hip_runtime.h>
#include <hip/hip_bf16.h>

#define NN 50000
#define EE 800000
#define IN_DIM 256
#define HID 64
#define HEADS 6
#define D1 384            // HEADS*HID
#define OUT_DIM 32
#define NEG_SLOPE 0.2f
#define CAP 128           // edge chunk per node held in LDS
#define NBLK 196          // ceil(50000/256)

typedef unsigned int uint32;
typedef unsigned short ushort_t;
typedef short short8 __attribute__((ext_vector_type(8)));
typedef float f32x4 __attribute__((ext_vector_type(4)));
typedef float f32x2 __attribute__((ext_vector_type(2)));
typedef ushort_t ushort8 __attribute__((ext_vector_type(8)));

__device__ __forceinline__ ushort_t f2bf(float f) {
    uint32 u = __builtin_bit_cast(uint32, f);
    u += 0x7fffu + ((u >> 16) & 1u);
    return (ushort_t)(u >> 16);
}
__device__ __forceinline__ float bf2f(ushort_t s) {
    uint32 u = ((uint32)s) << 16;
    return __builtin_bit_cast(float, u);
}
// dword d holds std channels (2d) in low half, (2d+1) in high half
__device__ __forceinline__ float lo16(uint32 d) { return __builtin_bit_cast(float, d << 16); }
__device__ __forceinline__ float hi16(uint32 d) { return __builtin_bit_cast(float, d & 0xffff0000u); }

// ---------------- fused prep: w1t (blocks 0..95), w2t (96..143), deg=0 (144..339) ----------------

__global__ __launch_bounds__(256) void prep_kernel(const float* __restrict__ W1,
                                                   ushort_t* __restrict__ W1Tb,
                                                   const float* __restrict__ W2,
                                                   ushort_t* __restrict__ W2Tb,
                                                   int* __restrict__ deg) {
    int bx = blockIdx.x;
    if (bx < 96) {
        __shared__ float tile[32][33];
        int tx = threadIdx.x & 31, ty = threadIdx.x >> 5;   // 32x8
        int n0 = (bx % 12) * 32;
        int k0 = (bx / 12) * 32;
#pragma unroll
        for (int i = 0; i < 4; ++i)
            tile[ty + i * 8][tx] = W1[(k0 + ty + i * 8) * D1 + n0 + tx];
        __syncthreads();
#pragma unroll
        for (int i = 0; i < 4; ++i)
            W1Tb[(n0 + ty + i * 8) * IN_DIM + k0 + tx] = f2bf(tile[tx][ty + i * 8]);
    } else if (bx < 144) {
        int idx = (bx - 96) * 256 + threadIdx.x;   // 0..12287
        if (idx < D1 * OUT_DIM) {
            int k = idx >> 5, n = idx & 31;
            W2Tb[n * D1 + k] = f2bf(W2[idx]);
        }
    } else {
        int i = (bx - 144) * 256 + threadIdx.x;
        if (i < NN) deg[i] = 0;
    }
}

// ---------------- CSR build ----------------

__global__ void hist_kernel(const int* __restrict__ dst, int* __restrict__ deg) {
    int i = blockIdx.x * 256 + threadIdx.x;
    if (i < EE) atomicAdd(&deg[dst[i]], 1);
}

// deg is read-side +1 (self-loop).
__global__ __launch_bounds__(256) void scan1_kernel(const int* __restrict__ deg,
                                                    int* __restrict__ blockSums) {
    int t = threadIdx.x;
    int i = blockIdx.x * 256 + t;
    int v = (i < NN) ? (deg[i] + 1) : 0;
#pragma unroll
    for (int o = 32; o; o >>= 1) v += __shfl_xor(v, o);
    __shared__ int ws[4];
    if ((t & 63) == 0) ws[t >> 6] = v;
    __syncthreads();
    if (t == 0) blockSums[blockIdx.x] = ws[0] + ws[1] + ws[2] + ws[3];
}

__global__ __launch_bounds__(256) void scan2_kernel(const int* __restrict__ blockSums,
                                                    int* __restrict__ blockPrefix,
                                                    int* __restrict__ offsets) {
    int t = threadIdx.x;
    int lane = t & 63, w = t >> 6;
    int v = (t < NBLK) ? blockSums[t] : 0;
    int x = v;
#pragma unroll
    for (int o = 1; o < 64; o <<= 1) {
        int y = __shfl_up(x, o);
        if (lane >= o) x += y;
    }
    __shared__ int ws[4];
    if (lane == 63) ws[w] = x;
    __syncthreads();
    int wpre = 0;
#pragma unroll
    for (int k = 0; k < 4; ++k) if (k < w) wpre += ws[k];
    int incl = x + wpre;
    if (t < NBLK) blockPrefix[t] = incl - v;
    if (t == NBLK - 1) offsets[NN] = incl;   // total == EE+NN
}

__global__ __launch_bounds__(256) void scan3_kernel(const int* __restrict__ deg,
                                                    const int* __restrict__ blockPrefix,
                                                    int* __restrict__ offsets,
                                                    int* __restrict__ cursor) {
    int t = threadIdx.x;
    int i = blockIdx.x * 256 + t;
    int lane = t & 63, w = t >> 6;
    int v = (i < NN) ? (deg[i] + 1) : 0;
    int x = v;
#pragma unroll
    for (int o = 1; o < 64; o <<= 1) {
        int y = __shfl_up(x, o);
        if (lane >= o) x += y;
    }
    __shared__ int ws[4];
    if (lane == 63) ws[w] = x;
    __syncthreads();
    int wpre = 0;
#pragma unroll
    for (int k = 0; k < 4; ++k) if (k < w) wpre += ws[k];
    int excl = x + wpre - v + blockPrefix[blockIdx.x];
    if (i < NN) { offsets[i] = excl; cursor[i] = excl; }
}

__global__ void scatter_kernel(const int* __restrict__ src, const int* __restrict__ dst,
                               int* __restrict__ cursor, int* __restrict__ srcIdx) {
    int i = blockIdx.x * 256 + threadIdx.x;
    if (i >= EE + NN) return;
    int s, d;
    if (i < EE) { s = src[i]; d = dst[i]; }
    else        { s = i - EE; d = s; }
    int pos = atomicAdd(&cursor[d], 1);
    srcIdx[pos] = s;
}

// ---------------- GEMM1: H1b = bf16( x @ W1 ) via MFMA, fused a_src1/a_dst1 ----------------
// 128-row x 384-col block tile, 512 threads = 8 waves: rg=wid>>2 (row half), cg=wid&3 (96-col group).
// K=256 in 4 steps of 64. (Round-8 proven config.)

#define G1_BM 128
#define G1_BK 64

__global__ __launch_bounds__(512) void gemm1_kernel(const float* __restrict__ A,
                                                    const ushort_t* __restrict__ Bt,
                                                    const float* __restrict__ att_src,
                                                    const float* __restrict__ att_dst,
                                                    ushort_t* __restrict__ Cb,
                                                    float* __restrict__ a_src1,
                                                    float* __restrict__ a_dst1) {
    __shared__ __align__(16) ushort_t As[G1_BM][G1_BK];   // 16 KB, 16B-chunk XOR swizzle
    __shared__ __align__(16) ushort_t Bs[D1][G1_BK];      // 48 KB, same swizzle
    __shared__ float redS[G1_BM][8];                      // 4 KB: [row][cg*2+headslot]
    __shared__ float redD[G1_BM][8];                      // 4 KB
    int t = threadIdx.x;
    int m0 = blockIdx.x * G1_BM;
    int wid = t >> 6, lane = t & 63;
    int rg = wid >> 2, cg = wid & 3;
    int lrow = lane & 15, lk = lane >> 4;
    f32x4 acc[4][6] = {};
    for (int k0 = 0; k0 < IN_DIM; k0 += G1_BK) {
        // stage A (f32 -> bf16): 128 rows x 8 chunks(16B) = 1024 chunks, 2/thread
        {
            int r = t >> 3, c = t & 7;
#pragma unroll
            for (int p = 0; p < 2; ++p) {
                int row = p * 64 + r;
                int gr = m0 + row;
                float4 v0 = make_float4(0.f, 0.f, 0.f, 0.f), v1 = v0;
                if (gr < NN) {
                    const float* g = &A[(size_t)gr * IN_DIM + k0 + c * 8];
                    v0 = *reinterpret_cast<const float4*>(g);
                    v1 = *reinterpret_cast<const float4*>(g + 4);
                }
                ushort8 u;
                u[0] = f2bf(v0.x); u[1] = f2bf(v0.y); u[2] = f2bf(v0.z); u[3] = f2bf(v0.w);
                u[4] = f2bf(v1.x); u[5] = f2bf(v1.y); u[6] = f2bf(v1.z); u[7] = f2bf(v1.w);
                *reinterpret_cast<ushort8*>(&As[row][(c ^ (row & 7)) * 8]) = u;
            }
        }
        // stage B: 384 rows x 8 chunks = 3072 chunks, 6/thread
        {
            int r = t >> 3, c = t & 7;
#pragma unroll
            for (int p = 0; p < 6; ++p) {
                int row = p * 64 + r;
                ushort8 u = *reinterpret_cast<const ushort8*>(&Bt[row * IN_DIM + k0 + c * 8]);
                *reinterpret_cast<ushort8*>(&Bs[row][(c ^ (row & 7)) * 8]) = u;
            }
        }
        __syncthreads();
#pragma unroll
        for (int kk = 0; kk < G1_BK; kk += 32) {
            int ckb = (kk >> 3) + lk;
            short8 af[4];
#pragma unroll
            for (int fm = 0; fm < 4; ++fm) {
                int m = rg * 64 + fm * 16 + lrow;
                af[fm] = *reinterpret_cast<const short8*>(&As[m][(ckb ^ (m & 7)) * 8]);
            }
#pragma unroll
            for (int fn = 0; fn < 6; ++fn) {
                int n = cg * 96 + fn * 16 + lrow;
                short8 bfv = *reinterpret_cast<const short8*>(&Bs[n][(ckb ^ (n & 7)) * 8]);
#pragma unroll
                for (int fm = 0; fm < 4; ++fm)
                    acc[fm][fn] = __builtin_amdgcn_mfma_f32_16x16x32_bf16(af[fm], bfv, acc[fm][fn], 0, 0, 0);
            }
        }
        __syncthreads();
    }
    // att values for this thread's 6 columns
    float atS[6], atD[6];
#pragma unroll
    for (int fn = 0; fn < 6; ++fn) {
        int col = cg * 96 + fn * 16 + lrow;
        atS[fn] = att_src[col];
        atD[fn] = att_dst[col];
    }
    int split = (cg & 1) ? 2 : 4;   // fn < split -> headslot 0, else headslot 1
    // epilogue: C/D layout col = lane&15, row = (lane>>4)*4 + reg
#pragma unroll
    for (int fm = 0; fm < 4; ++fm) {
#pragma unroll
        for (int r = 0; r < 4; ++r) {
            int rowl = rg * 64 + fm * 16 + lk * 4 + r;
            int row = m0 + rowl;
            float vsA = 0.f, vsB = 0.f, vdA = 0.f, vdB = 0.f;
#pragma unroll
            for (int fn = 0; fn < 6; ++fn) {
                float v = acc[fm][fn][r];
                if (fn < split) { vsA += v * atS[fn]; vdA += v * atD[fn]; }
                else            { vsB += v * atS[fn]; vdB += v * atD[fn]; }
            }
#pragma unroll
            for (int o = 8; o; o >>= 1) {
                vsA += __shfl_xor(vsA, o); vsB += __shfl_xor(vsB, o);
                vdA += __shfl_xor(vdA, o); vdB += __shfl_xor(vdB, o);
            }
            if (lrow == 0) {
                redS[rowl][cg * 2 + 0] = vsA; redS[rowl][cg * 2 + 1] = vsB;
                redD[rowl][cg * 2 + 0] = vdA; redD[rowl][cg * 2 + 1] = vdB;
            }
            if (row < NN) {
#pragma unroll
                for (int fn = 0; fn < 6; ++fn) {
                    int col = cg * 96 + fn * 16 + lrow;
                    Cb[(size_t)row * D1 + col] = f2bf(acc[fm][fn][r]);
                }
            }
        }
    }
    __syncthreads();
    if (t < G1_BM) {
        int row = m0 + t;
        if (row < NN) {
            // head <- slot mapping: h0=s0; h1=s1+s2; h2=s3; h3=s4; h4=s5+s6; h5=s7
            float s0 = redS[t][0], s1 = redS[t][1] + redS[t][2], s2 = redS[t][3];
            float s3 = redS[t][4], s4 = redS[t][5] + redS[t][6], s5 = redS[t][7];
            float d0 = redD[t][0], d1 = redD[t][1] + redD[t][2], d2 = redD[t][3];
            float d3 = redD[t][4], d4 = redD[t][5] + redD[t][6], d5 = redD[t][7];
            float* ps = &a_src1[(size_t)row * HEADS];
            float* pd = &a_dst1[(size_t)row * HEADS];
            ps[0] = s0; ps[1] = s1; ps[2] = s2; ps[3] = s3; ps[4] = s4; ps[5] = s5;
            pd[0] = d0; pd[1] = d1; pd[2] = d2; pd[3] = d3; pd[4] = d4; pd[5] = d5;
        }
    }
}

// ---------------- layer-1 aggregation: exp-direct two-phase, deep-pipelined ----------------

__global__ __launch_bounds__(256, 4) void agg1_kernel(const uint32* __restrict__ H1d,
                                                      const float* __restrict__ a_src,
                                                      const float* __restrict__ a_dst,
                                                      const int* __restrict__ offsets,
                                                      const int* __restrict__ srcIdx,
                                                      const float* __restrict__ b1,
                                                      uint32* __restrict__ out1d) {
    __shared__ float pl[4][HEADS][CAP + 1];   // ~12.4 KB
    __shared__ int   sl[4][CAP];              // 2 KB
    int w = threadIdx.x >> 6, lane = threadIdx.x & 63;
    int hb = lane >> 5;
    int n = blockIdx.x * 4 + w;
    const float2* asv = (const float2*)a_src;
    float ad[HEADS];
#pragma unroll
    for (int h = 0; h < HEADS; ++h) ad[h] = a_dst[n * HEADS + h];
    float ldn[HEADS] = {0.f, 0.f, 0.f, 0.f, 0.f, 0.f};
    float acc[6] = {0.f, 0.f, 0.f, 0.f, 0.f, 0.f};
    int beg = offsets[n], end = offsets[n + 1];
    for (int cbeg = beg; cbeg < end; cbeg += CAP) {
        int L = end - cbeg; if (L > CAP) L = CAP;
        // ---- phase A: lanes over edges ----
        for (int tI = lane; tI < L; tI += 64) {
            int s = srcIdx[cbeg + tI];
            sl[w][tI] = s;
            float2 e0 = asv[s * 3 + 0];
            float2 e1 = asv[s * 3 + 1];
            float2 e2 = asv[s * 3 + 2];
            float ev[6] = {e0.x, e0.y, e1.x, e1.y, e2.x, e2.y};
#pragma unroll
            for (int h = 0; h < HEADS; ++h) {
                float e = ev[h] + ad[h];
                e = e > 0.f ? e : NEG_SLOPE * e;
                float p = __expf(e);
                pl[w][h][tI] = p;
                ldn[h] += p;
            }
        }
        // ---- phase B: lanes over dwords, 4 edges / 12 gathers in flight ----
        int j = 0;
        for (; j + 4 <= L; j += 4) {
            int s0 = sl[w][j], s1 = sl[w][j + 1], s2 = sl[w][j + 2], s3 = sl[w][j + 3];
            const uint32* h0 = H1d + (size_t)s0 * 192 + lane;
            const uint32* h1 = H1d + (size_t)s1 * 192 + lane;
            const uint32* h2 = H1d + (size_t)s2 * 192 + lane;
            const uint32* h3 = H1d + (size_t)s3 * 192 + lane;
            uint32 a0 = h0[0], a1 = h0[64], a2 = h0[128];
            uint32 b0 = h1[0], b1v_ = h1[64], b2 = h1[128];
            uint32 c0 = h2[0], c1 = h2[64], c2 = h2[128];
            uint32 d0 = h3[0], d1 = h3[64], d2 = h3[128];
            float p00 = pl[w][hb][j],     p01 = pl[w][2 + hb][j],     p02 = pl[w][4 + hb][j];
            float p10 = pl[w][hb][j + 1], p11 = pl[w][2 + hb][j + 1], p12 = pl[w][4 + hb][j + 1];
            float p20 = pl[w][hb][j + 2], p21 = pl[w][2 + hb][j + 2], p22 = pl[w][4 + hb][j + 2];
            float p30 = pl[w][hb][j + 3], p31 = pl[w][2 + hb][j + 3], p32 = pl[w][4 + hb][j + 3];
            acc[0] += p00 * lo16(a0); acc[1] += p00 * hi16(a0);
            acc[2] += p01 * lo16(a1); acc[3] += p01 * hi16(a1);
            acc[4] += p02 * lo16(a2); acc[5] += p02 * hi16(a2);
            acc[0] += p10 * lo16(b0); acc[1] += p10 * hi16(b0);
            acc[2] += p11 * lo16(b1v_); acc[3] += p11 * hi16(b1v_);
            acc[4] += p12 * lo16(b2); acc[5] += p12 * hi16(b2);
            acc[0] += p20 * lo16(c0); acc[1] += p20 * hi16(c0);
            acc[2] += p21 * lo16(c1); acc[3] += p21 * hi16(c1);
            acc[4] += p22 * lo16(c2); acc[5] += p22 * hi16(c2);
            acc[0] += p30 * lo16(d0); acc[1] += p30 * hi16(d0);
            acc[2] += p31 * lo16(d1); acc[3] += p31 * hi16(d1);
            acc[4] += p32 * lo16(d2); acc[5] += p32 * hi16(d2);
        }
        for (; j < L; ++j) {
            int s0 = sl[w][j];
            const uint32* h0 = H1d + (size_t)s0 * 192 + lane;
            uint32 x0 = h0[0], x1 = h0[64], x2 = h0[128];
            float p0 = pl[w][hb][j], p1 = pl[w][2 + hb][j], p2 = pl[w][4 + hb][j];
            acc[0] += p0 * lo16(x0); acc[1] += p0 * hi16(x0);
            acc[2] += p1 * lo16(x1); acc[3] += p1 * hi16(x1);
            acc[4] += p2 * lo16(x2); acc[5] += p2 * hi16(x2);
        }
    }
#pragma unroll
    for (int h = 0; h < HEADS; ++h) {
#pragma unroll
        for (int o = 32; o; o >>= 1) ldn[h] += __shfl_xor(ldn[h], o);
    }
    float dsel[3];
#pragma unroll
    for (int k = 0; k < 3; ++k) dsel[k] = hb ? ldn[2 * k + 1] : ldn[2 * k];
    const float2* b1v = (const float2*)b1;
#pragma unroll
    for (int k = 0; k < 3; ++k) {
        float2 bb = b1v[k * 64 + lane];
        float v0 = fmaxf(acc[2 * k]     / dsel[k] + bb.x, 0.f);
        float v1 = fmaxf(acc[2 * k + 1] / dsel[k] + bb.y, 0.f);
        uint32 pk = (uint32)f2bf(v0) | ((uint32)f2bf(v1) << 16);
        __builtin_nontemporal_store(pk, &out1d[(size_t)n * 192 + k * 64 + lane]);
    }
}

// ---------------- GEMM2 via MFMA (+ fused a_src2/a_dst2) ----------------

#define G2_ROWS 256

__global__ __launch_bounds__(256) void gemm2_kernel(const ushort_t* __restrict__ Xb,
                                                    const ushort_t* __restrict__ W2Tb,
                                                    const float* __restrict__ att_src2,
                                                    const float* __restrict__ att_dst2,
                                                    ushort_t* __restrict__ H2b,
                                                    float* __restrict__ a_src2,
                                                    float* __restrict__ a_dst2) {
    __shared__ __align__(16) ushort_t Ws[OUT_DIM][D1];     // 24 KB, swizzled per 64-span
    __shared__ __align__(16) ushort_t Xs[G2_ROWS][64];     // 32 KB, swizzled
    int t = threadIdx.x;
    int wid = t >> 6, lane = t & 63;
    int lrow = lane & 15, lk = lane >> 4;
    int m0 = blockIdx.x * G2_ROWS;
#pragma unroll
    for (int p = 0; p < 6; ++p) {
        int chunk = p * 256 + t;
        int nr = chunk / 48, c = chunk % 48;
        ushort8 u = *reinterpret_cast<const ushort8*>(&W2Tb[nr * D1 + c * 8]);
        int span = c >> 3, cc = c & 7;
        *reinterpret_cast<ushort8*>(&Ws[nr][(cc ^ (nr & 7)) * 8 + span * 64]) = u;
    }
    f32x4 acc[4][2] = {};
    for (int kc = 0; kc < 6; ++kc) {
        int k0 = kc * 64;
        {
            int r = t >> 3, c = t & 7;
#pragma unroll
            for (int p = 0; p < 8; ++p) {
                int row = p * 32 + r;
                int gr = m0 + row;
                ushort8 u = {0, 0, 0, 0, 0, 0, 0, 0};
                if (gr < NN) u = *reinterpret_cast<const ushort8*>(&Xb[(size_t)gr * D1 + k0 + c * 8]);
                *reinterpret_cast<ushort8*>(&Xs[row][(c ^ (row & 7)) * 8]) = u;
            }
        }
        __syncthreads();
#pragma unroll
        for (int kk = 0; kk < 64; kk += 32) {
            int ckb = (kk >> 3) + lk;
            short8 af[4];
#pragma unroll
            for (int fm = 0; fm < 4; ++fm) {
                int mm = wid * 64 + fm * 16 + lrow;
                af[fm] = *reinterpret_cast<const short8*>(&Xs[mm][(ckb ^ (mm & 7)) * 8]);
            }
#pragma unroll
            for (int fn = 0; fn < 2; ++fn) {
                int nn2 = fn * 16 + lrow;
                short8 bfv = *reinterpret_cast<const short8*>(&Ws[nn2][(ckb ^ (nn2 & 7)) * 8 + kc * 64]);
#pragma unroll
                for (int fm = 0; fm < 4; ++fm)
                    acc[fm][fn] = __builtin_amdgcn_mfma_f32_16x16x32_bf16(af[fm], bfv, acc[fm][fn], 0, 0, 0);
            }
        }
        __syncthreads();
    }
    float as2a = att_src2[lrow], as2b = att_src2[16 + lrow];
    float ad2a = att_dst2[lrow], ad2b = att_dst2[16 + lrow];
#pragma unroll
    for (int fm = 0; fm < 4; ++fm) {
#pragma unroll
        for (int r = 0; r < 4; ++r) {
            int row = m0 + wid * 64 + fm * 16 + lk * 4 + r;
            float h0 = acc[fm][0][r], h1 = acc[fm][1][r];
            float vs = h0 * as2a + h1 * as2b;
            float vd = h0 * ad2a + h1 * ad2b;
#pragma unroll
            for (int o = 8; o; o >>= 1) {
                vs += __shfl_xor(vs, o);
                vd += __shfl_xor(vd, o);
            }
            if (row < NN) {
                H2b[(size_t)row * OUT_DIM + lrow]      = f2bf(h0);
                H2b[(size_t)row * OUT_DIM + 16 + lrow] = f2bf(h1);
                if (lrow == 0) { a_src2[row] = vs; a_dst2[row] = vd; }
            }
        }
    }
}

// ---------------- layer-2 aggregation: exp-direct (+b2) -> d_out ----------------

__global__ __launch_bounds__(256, 4) void agg2_kernel(const ushort_t* __restrict__ H2b,
                                                      const float* __restrict__ a_src,
                                                      const float* __restrict__ a_dst,
                                                      const int* __restrict__ offsets,
                                                      const int* __restrict__ srcIdx,
                                                      const float* __restrict__ b2,
                                                      float* __restrict__ out) {
    __shared__ float pl[4][CAP];
    __shared__ int   sl[4][CAP];
    int w = threadIdx.x >> 6, lane = threadIdx.x & 63;
    int n = blockIdx.x * 4 + w;
    int q = lane & 15, par = lane >> 4;   // 4 edges in parallel, lane covers chans 2q,2q+1
    const uint32* H2d = (const uint32*)H2b;
    float ad = a_dst[n];
    float ldn = 0.f, ax = 0.f, ay = 0.f;
    int beg = offsets[n], end = offsets[n + 1];
    for (int cbeg = beg; cbeg < end; cbeg += CAP) {
        int L = end - cbeg; if (L > CAP) L = CAP;
        for (int tI = lane; tI < L; tI += 64) {
            int s = srcIdx[cbeg + tI];
            sl[w][tI] = s;
            float e = a_src[s] + ad;
            e = e > 0.f ? e : NEG_SLOPE * e;
            float p = __expf(e);
            pl[w][tI] = p;
            ldn += p;
        }
        int j = 0;
        for (; j + 8 <= L; j += 8) {
            int s0 = sl[w][j + par], s1 = sl[w][j + 4 + par];
            float p0 = pl[w][j + par], p1 = pl[w][j + 4 + par];
            uint32 d0 = H2d[(size_t)s0 * 16 + q];
            uint32 d1 = H2d[(size_t)s1 * 16 + q];
            ax += p0 * lo16(d0) + p1 * lo16(d1);
            ay += p0 * hi16(d0) + p1 * hi16(d1);
        }
        for (; j < L; j += 4) {
            int jj = j + par;
            if (jj < L) {
                int s = sl[w][jj];
                float p = pl[w][jj];
                uint32 d = H2d[(size_t)s * 16 + q];
                ax += p * lo16(d);
                ay += p * hi16(d);
            }
        }
    }
#pragma unroll
    for (int o = 32; o; o >>= 1) ldn += __shfl_xor(ldn, o);
    ax += __shfl_xor(ax, 16); ax += __shfl_xor(ax, 32);
    ay += __shfl_xor(ay, 16); ay += __shfl_xor(ay, 32);
    if (lane < 16) {
        float2 bb = ((const float2*)b2)[q];
        f32x2 o;
        o[0] = ax / ldn + bb.x;
        o[1] = ay / ldn + bb.y;
        __builtin_nontemporal_store(o, (f32x2*)&out[(size_t)n * 32 + q * 2]);
    }
}

// ---------------- launch ----------------

static inline size_t align256(size_t x) { return (x + 255) & ~size_t(255); }

extern "C" void kernel_launch(void* const* d_in, const int* in_sizes, int n_in,
                              void* d_out, int out_size, void* d_ws, size_t ws_size,
                              hipStream_t stream) {
    const float* x        = (const float*)d_in[0];
    const int*   ei       = (const int*)d_in[1];
    const float* W1       = (const float*)d_in[2];
    const float* att_src1 = (const float*)d_in[3];
    const float* att_dst1 = (const float*)d_in[4];
    const float* b1       = (const float*)d_in[5];
    const float* W2       = (const float*)d_in[6];
    const float* att_src2 = (const float*)d_in[7];
    const float* att_dst2 = (const float*)d_in[8];
    const float* b2       = (const float*)d_in[9];
    float* out = (float*)d_out;

    const int* e_src = ei;
    const int* e_dst = ei + EE;

    char* p = (char*)d_ws;
    ushort_t* H1b   = (ushort_t*)p; p += align256(sizeof(ushort_t) * (size_t)NN * D1);
    ushort_t* OUT1b = (ushort_t*)p; p += align256(sizeof(ushort_t) * (size_t)NN * D1);
    ushort_t* H2b   = (ushort_t*)p; p += align256(sizeof(ushort_t) * (size_t)NN * OUT_DIM);
    ushort_t* W1Tb  = (ushort_t*)p; p += align256(sizeof(ushort_t) * D1 * IN_DIM);
    ushort_t* W2Tb  = (ushort_t*)p; p += align256(sizeof(ushort_t) * D1 * OUT_DIM);
    float* AS1  = (float*)p; p += align256(sizeof(float) * NN * HEADS);
    float* AD1  = (float*)p; p += align256(sizeof(float) * NN * HEADS);
    float* AS2  = (float*)p; p += align256(sizeof(float) * NN);
    float* AD2  = (float*)p; p += align256(sizeof(float) * NN);
    int*   DEG  = (int*)p;   p += align256(sizeof(int) * NN);
    int*   OFF  = (int*)p;   p += align256(sizeof(int) * (NN + 1));
    int*   CUR  = (int*)p;   p += align256(sizeof(int) * NN);
    int*   BSUM = (int*)p;   p += align256(sizeof(int) * NBLK);
    int*   BPRE = (int*)p;   p += align256(sizeof(int) * NBLK);
    int*   SIDX = (int*)p;   p += align256(sizeof(int) * (EE + NN));

    // prep (w1t + w2t + deg=0 fused) then CSR build
    prep_kernel<<<340, 256, 0, stream>>>(W1, W1Tb, W2, W2Tb, DEG);
    hist_kernel<<<(EE + 255) / 256, 256, 0, stream>>>(e_dst, DEG);
    scan1_kernel<<<NBLK, 256, 0, stream>>>(DEG, BSUM);
    scan2_kernel<<<1, 256, 0, stream>>>(BSUM, BPRE, OFF);
    scan3_kernel<<<NBLK, 256, 0, stream>>>(DEG, BPRE, OFF, CUR);
    scatter_kernel<<<(EE + NN + 255) / 256, 256, 0, stream>>>(e_src, e_dst, CUR, SIDX);

    // layer 1
    gemm1_kernel<<<(NN + G1_BM - 1) / G1_BM, 512, 0, stream>>>(x, W1Tb, att_src1, att_dst1, H1b, AS1, AD1);
    agg1_kernel<<<NN / 4, 256, 0, stream>>>((const uint32*)H1b, AS1, AD1, OFF, SIDX, b1, (uint32*)OUT1b);

    // layer 2
    gemm2_kernel<<<(NN + G2_ROWS - 1) / G2_ROWS, 256, 0, stream>>>(OUT1b, W2Tb, att_src2, att_dst2, H2b, AS2, AD2);
    agg2_kernel<<<NN / 4, 256, 0, stream>>>(H2b, AS2, AD2, OFF, SIDX, b2, out);
}